// Round 1
// baseline (65.585 us; speedup 1.0000x reference)
//
#include <hip/hip_runtime.h>

#define NUM_GRAPHS 1024
#define BLOCK 256
#define GROUPS_PER_THREAD 2                       // 4-node groups per thread
#define NODES_PER_BLOCK (BLOCK * GROUPS_PER_THREAD * 4)  // 2048

// ---------------------------------------------------------------------------
// Kernel 1: per-node |pred-target| sums segmented by (sorted) batch id, plus
// global force-norm sum. LDS-accumulated per block, flushed via global atomics.
// ---------------------------------------------------------------------------
__global__ __launch_bounds__(BLOCK) void mae_seg_kernel(
    const float* __restrict__ pred,
    const float* __restrict__ target,
    const int*   __restrict__ batch,
    const float* __restrict__ x,
    float* __restrict__ ws_sum,    // [NUM_GRAPHS]
    float* __restrict__ ws_cnt,    // [NUM_GRAPHS]
    float* __restrict__ ws_force,  // [1]
    int n)
{
    __shared__ float ls[NUM_GRAPHS];
    __shared__ float lc[NUM_GRAPHS];
    __shared__ float lf[BLOCK / 64];

    const int tid = threadIdx.x;
    for (int i = tid; i < NUM_GRAPHS; i += BLOCK) { ls[i] = 0.f; lc[i] = 0.f; }
    __syncthreads();

    // ---- segmented |pred-target| accumulation (run-length per thread) ----
    const float4* p4 = (const float4*)pred;
    const float4* t4 = (const float4*)target;
    const int4*   b4 = (const int4*)batch;

    int   cur_id  = -1;
    float cur_sum = 0.f;
    float cur_cnt = 0.f;

    const int group_base = blockIdx.x * (BLOCK * GROUPS_PER_THREAD);
#pragma unroll
    for (int v = 0; v < GROUPS_PER_THREAD; ++v) {
        const int g    = group_base + v * BLOCK + tid;  // 4-node group index
        const int node = g * 4;
        if (node + 3 < n) {
            float4 pa = p4[g * 3 + 0], pb = p4[g * 3 + 1], pc = p4[g * 3 + 2];
            float4 ta = t4[g * 3 + 0], tb = t4[g * 3 + 1], tc = t4[g * 3 + 2];
            float asum[4];
            asum[0] = fabsf(pa.x - ta.x) + fabsf(pa.y - ta.y) + fabsf(pa.z - ta.z);
            asum[1] = fabsf(pa.w - ta.w) + fabsf(pb.x - tb.x) + fabsf(pb.y - tb.y);
            asum[2] = fabsf(pb.z - tb.z) + fabsf(pb.w - tb.w) + fabsf(pc.x - tc.x);
            asum[3] = fabsf(pc.y - tc.y) + fabsf(pc.z - tc.z) + fabsf(pc.w - tc.w);
            int4 bb = b4[g];
            int bid[4] = {bb.x, bb.y, bb.z, bb.w};
#pragma unroll
            for (int r = 0; r < 4; ++r) {
                if (bid[r] != cur_id) {
                    if (cur_id >= 0) {
                        atomicAdd(&ls[cur_id], cur_sum);
                        atomicAdd(&lc[cur_id], cur_cnt);
                    }
                    cur_id = bid[r]; cur_sum = 0.f; cur_cnt = 0.f;
                }
                cur_sum += asum[r];
                cur_cnt += 1.f;
            }
        } else if (node < n) {
            for (int r = 0; r < 4; ++r) {
                const int nd = node + r;
                if (nd >= n) break;
                float a = fabsf(pred[nd * 3 + 0] - target[nd * 3 + 0])
                        + fabsf(pred[nd * 3 + 1] - target[nd * 3 + 1])
                        + fabsf(pred[nd * 3 + 2] - target[nd * 3 + 2]);
                int b = batch[nd];
                if (b != cur_id) {
                    if (cur_id >= 0) {
                        atomicAdd(&ls[cur_id], cur_sum);
                        atomicAdd(&lc[cur_id], cur_cnt);
                    }
                    cur_id = b; cur_sum = 0.f; cur_cnt = 0.f;
                }
                cur_sum += a;
                cur_cnt += 1.f;
            }
        }
    }
    if (cur_id >= 0) {
        atomicAdd(&ls[cur_id], cur_sum);
        atomicAdd(&lc[cur_id], cur_cnt);
    }

    // ---- force: coalesced float4 over flat x; pair (x3,x4) via shfl_xor ----
    // float4 index F covers floats 4F..4F+3 of x. Even F (row F/2): comp .w is
    // x[row*8+3]; odd F (row (F-1)/2): comp .x is x[row*8+4]. Lane parity ==
    // F parity (base and v*BLOCK are even), so lanes 2k/2k+1 hold a row's pair.
    const float4* x4 = (const float4*)x;
    const int nx4 = n * 2;                       // total float4s in x
    const int xbase = blockIdx.x * (NODES_PER_BLOCK * 2);
    float fsum = 0.f;
#pragma unroll
    for (int v = 0; v < NODES_PER_BLOCK * 2 / BLOCK; ++v) {   // 16 iters
        const int idx = xbase + v * BLOCK + tid;
        float val = 0.f;
        if (idx < nx4) {
            float4 xv = x4[idx];
            val = (tid & 1) ? xv.x : xv.w;
        }
        float other = __shfl_xor(val, 1, 64);
        if ((tid & 1) == 0 && idx < nx4) {
            fsum += sqrtf(val * val + other * other);
        }
    }
#pragma unroll
    for (int off = 32; off > 0; off >>= 1) fsum += __shfl_down(fsum, off, 64);
    if ((tid & 63) == 0) lf[tid >> 6] = fsum;
    __syncthreads();
    if (tid == 0) {
        float tot = 0.f;
        for (int w = 0; w < BLOCK / 64; ++w) tot += lf[w];
        atomicAdd(ws_force, tot);
    }

    // ---- flush per-block LDS partials ----
    for (int i = tid; i < NUM_GRAPHS; i += BLOCK) {
        float c = lc[i];
        if (c != 0.f) {
            atomicAdd(&ws_sum[i], ls[i]);
            atomicAdd(&ws_cnt[i], c);
        }
    }
}

// ---------------------------------------------------------------------------
// Kernel 2: finalize — mean over graphs of seg_sum/(max(cnt,1)*3), scale.
// ---------------------------------------------------------------------------
__global__ __launch_bounds__(NUM_GRAPHS) void finalize_kernel(
    const float* __restrict__ ws_sum,
    const float* __restrict__ ws_cnt,
    const float* __restrict__ ws_force,
    float* __restrict__ out)
{
    __shared__ float red[NUM_GRAPHS];
    const int t = threadIdx.x;
    red[t] = ws_sum[t] / (fmaxf(ws_cnt[t], 1.0f) * 3.0f);
    __syncthreads();
    for (int s = NUM_GRAPHS / 2; s > 0; s >>= 1) {
        if (t < s) red[t] += red[t + s];
        __syncthreads();
    }
    if (t == 0) {
        const float scale = fmaxf(ws_force[0], 0.1f);
        out[0] = (red[0] / (float)NUM_GRAPHS) * scale * 100.0f;
    }
}

extern "C" void kernel_launch(void* const* d_in, const int* in_sizes, int n_in,
                              void* d_out, int out_size, void* d_ws, size_t ws_size,
                              hipStream_t stream) {
    const float* pred   = (const float*)d_in[0];
    const float* target = (const float*)d_in[1];
    const int*   batch  = (const int*)d_in[2];
    const float* x      = (const float*)d_in[3];
    float* out = (float*)d_out;

    const int n = in_sizes[2];                  // N nodes (batch vector length)

    float* ws_sum   = (float*)d_ws;             // [1024]
    float* ws_cnt   = ws_sum + NUM_GRAPHS;      // [1024]
    float* ws_force = ws_cnt + NUM_GRAPHS;      // [1]

    hipMemsetAsync(d_ws, 0, (2 * NUM_GRAPHS + 1) * sizeof(float), stream);

    const int blocks = (n + NODES_PER_BLOCK - 1) / NODES_PER_BLOCK;
    mae_seg_kernel<<<blocks, BLOCK, 0, stream>>>(pred, target, batch, x,
                                                 ws_sum, ws_cnt, ws_force, n);
    finalize_kernel<<<1, NUM_GRAPHS, 0, stream>>>(ws_sum, ws_cnt, ws_force, out);
}